// Round 3
// baseline (550.905 us; speedup 1.0000x reference)
//
#include <hip/hip_runtime.h>
#include <hip/hip_bf16.h>

typedef unsigned short u16;
typedef unsigned int u32;
typedef short bf16x8 __attribute__((ext_vector_type(8)));
typedef float f32x4 __attribute__((ext_vector_type(4)));

__device__ __forceinline__ float bf2f(u32 bits16) {
    return __uint_as_float(bits16 << 16);
}
__device__ __forceinline__ u16 f2bf(float f) {
    u32 u = __float_as_uint(f);
    u32 r = (u + 0x7fffu + ((u >> 16) & 1u)) >> 16;   // RNE
    return (u16)r;
}

// ---------------- h (f32) -> hbf (bf16) ----------------
__global__ void k_conv_h(const float* __restrict__ h, u16* __restrict__ hbf, int total) {
    int i = (blockIdx.x * blockDim.x + threadIdx.x) * 4;
    if (i < total) {
        float4 val = *(const float4*)(h + i);
        u32 lo = ((u32)f2bf(val.y) << 16) | f2bf(val.x);
        u32 hi = ((u32)f2bf(val.w) << 16) | f2bf(val.z);
        uint2 o; o.x = lo; o.y = hi;
        *(uint2*)(hbf + i) = o;
    }
}

// ---------------- build B1 = [M^T ; Wv] (256x128 bf16), Wpbf (128x128 bf16) ----
// B1[j][k] = sum_t Wq[t][k]*Wk[t][j]  (j<128)   => g = hbf @ B1[j]rows
// B1[128+m][k] = Wv[m][k]                       => v = hbf @ those rows
__global__ void k_prep(const float* __restrict__ Wq, const float* __restrict__ Wk,
                       const float* __restrict__ Wv, const float* __restrict__ Wp,
                       u16* __restrict__ B1, u16* __restrict__ Wpbf) {
    int j = blockIdx.x;
    int k = threadIdx.x;  // 128 threads
    if (j < 128) {
        float s = 0.f;
        for (int t = 0; t < 128; t++) s += Wq[t * 128 + k] * Wk[t * 128 + j];
        B1[j * 128 + k] = f2bf(s);
    } else if (j < 256) {
        B1[j * 128 + k] = f2bf(Wv[(j - 128) * 128 + k]);
    } else {
        Wpbf[(j - 256) * 128 + k] = f2bf(Wp[(j - 256) * 128 + k]);
    }
}

// ---------------- degree histogram ----------------
__global__ void k_hist(const int* __restrict__ edges, int* __restrict__ deg, int E) {
    int e = blockIdx.x * blockDim.x + threadIdx.x;
    if (e < E) atomicAdd(&deg[edges[E + e]], 1);
}

// ---------------- exclusive scan (single block, 1024 threads) ----------------
__global__ void k_scan(const int* __restrict__ deg, int* __restrict__ offs,
                       int* __restrict__ cursor, int N, int E) {
    __shared__ int tmp[1024];
    int tid = threadIdx.x;
    int items = (N + 1023) >> 10;
    int start = tid * items;
    int end = min(start + items, N);
    int s = 0;
    for (int i = start; i < end; i++) s += deg[i];
    tmp[tid] = s;
    __syncthreads();
    for (int off = 1; off < 1024; off <<= 1) {
        int v = tmp[tid];
        int a = (tid >= off) ? tmp[tid - off] : 0;
        __syncthreads();
        tmp[tid] = v + a;
        __syncthreads();
    }
    int run = tmp[tid] - s;  // exclusive prefix
    for (int i = start; i < end; i++) {
        offs[i] = run; cursor[i] = run;
        run += deg[i];
    }
    if (tid == 1023) offs[N] = tmp[1023];
}

// ---------------- scatter edge srcs into CSR ----------------
__global__ void k_scatter(const int* __restrict__ edges, int* __restrict__ cursor,
                          int* __restrict__ esrc, int E) {
    int e = blockIdx.x * blockDim.x + threadIdx.x;
    if (e < E) {
        int dst = edges[E + e];
        int pos = atomicAdd(&cursor[dst], 1);
        esrc[pos] = edges[e];
    }
}

// ---------------- GEMM1: [g|v] = hbf @ B1^T  (out bf16) ----------------
// block: 256 thr (4 waves), 64 rows, 256 cols in 2 halves of 128
__launch_bounds__(256)
__global__ void k_gemm1(const u16* __restrict__ hbf, const u16* __restrict__ B1,
                        u16* __restrict__ g, u16* __restrict__ v, int N) {
    __shared__ u16 As[64 * 128];    // 16 KB, swizzled
    __shared__ u16 Bs[128 * 128];   // 32 KB, swizzled
    int tid = threadIdx.x;
    int rowBase = blockIdx.x * 64;
    int chunk = tid & 15, r0 = tid >> 4;

    for (int it = 0; it < 4; it++) {
        int r = r0 + it * 16;
        int gr = rowBase + r;
        uint4 val = make_uint4(0, 0, 0, 0);
        if (gr < N) val = *(const uint4*)(hbf + (size_t)gr * 128 + chunk * 8);
        *(uint4*)&As[r * 128 + ((chunk * 8) ^ ((r & 7) << 3))] = val;
    }

    int w = tid >> 6, l = tid & 63;
    int lr = l & 15, lq = l >> 4;

    for (int half = 0; half < 2; half++) {
        if (half) __syncthreads();  // all waves done reading Bs half 0
        for (int it = 0; it < 8; it++) {
            int r = r0 + it * 16;
            uint4 val = *(const uint4*)(B1 + (size_t)(half * 128 + r) * 128 + chunk * 8);
            *(uint4*)&Bs[r * 128 + ((chunk * 8) ^ ((r & 7) << 3))] = val;
        }
        __syncthreads();

        bf16x8 a[4];
        int ar = w * 16 + lr;
        for (int kk = 0; kk < 4; kk++)
            a[kk] = *(const bf16x8*)&As[ar * 128 + ((kk * 32 + lq * 8) ^ ((ar & 7) << 3))];

        for (int ct = 0; ct < 8; ct++) {
            int br = ct * 16 + lr;
            f32x4 acc = {0.f, 0.f, 0.f, 0.f};
            for (int kk = 0; kk < 4; kk++) {
                bf16x8 b = *(const bf16x8*)&Bs[br * 128 + ((kk * 32 + lq * 8) ^ ((br & 7) << 3))];
                acc = __builtin_amdgcn_mfma_f32_16x16x32_bf16(a[kk], b, acc, 0, 0, 0);
            }
            int j = ct * 16 + lr;  // col within this half
            for (int ri = 0; ri < 4; ri++) {
                int row = rowBase + w * 16 + lq * 4 + ri;
                if (row < N) {
                    u16 bv = f2bf(acc[ri]);
                    if (half == 0) g[(size_t)row * 128 + j] = bv;
                    else           v[(size_t)row * 128 + j] = bv;
                }
            }
        }
    }
}

// ---------------- fused edge kernel: one wave per dst node ----------------
// s_e = (g[dst] . hbf[src]) / sqrt(128);  agg[dst] = sum e^{s_e} v[src] / sum e^{s_e}
__launch_bounds__(256)
__global__ void k_edge(const u16* __restrict__ g, const u16* __restrict__ hbf,
                       const u16* __restrict__ vbf, const int* __restrict__ offs,
                       const int* __restrict__ esrc, u16* __restrict__ agg, int N) {
    int wid = (blockIdx.x * blockDim.x + threadIdx.x) >> 6;
    int lane = threadIdx.x & 63;
    if (wid >= N) return;
    const u32* g32 = (const u32*)g;
    const u32* h32 = (const u32*)hbf;
    const u32* v32 = (const u32*)vbf;
    u32 gv = g32[(size_t)wid * 64 + lane];
    float g0 = bf2f(gv & 0xffff), g1 = bf2f(gv >> 16);
    int e0 = offs[wid], e1 = offs[wid + 1];
    float acc0 = 0.f, acc1 = 0.f, denom = 0.f;
    const float sc = 0.08838834764831845f;  // 1/sqrt(128)
    for (int i = e0; i < e1; i++) {
        int src = esrc[i];
        u32 hv = h32[(size_t)src * 64 + lane];
        float p = g0 * bf2f(hv & 0xffff) + g1 * bf2f(hv >> 16);
        for (int m = 1; m < 64; m <<= 1) p += __shfl_xor(p, m, 64);
        float ew = __expf(p * sc);
        denom += ew;
        u32 vv = v32[(size_t)src * 64 + lane];
        acc0 += ew * bf2f(vv & 0xffff);
        acc1 += ew * bf2f(vv >> 16);
    }
    float inv = (denom > 0.f) ? 1.f / denom : 0.f;
    u32 o = ((u32)f2bf(acc1 * inv) << 16) | f2bf(acc0 * inv);
    ((u32*)agg)[(size_t)wid * 64 + lane] = o;
}

// ---------------- GEMM2: out = relu(agg @ Wp^T + bp + h)  (f32 out) ----------
__launch_bounds__(256)
__global__ void k_gemm2(const u16* __restrict__ aggbf, const u16* __restrict__ Wpbf,
                        const float* __restrict__ bp, const float* __restrict__ h,
                        float* __restrict__ out, int N) {
    __shared__ u16 As[64 * 128];    // 16 KB
    __shared__ u16 Bs[128 * 128];   // 32 KB
    int tid = threadIdx.x;
    int rowBase = blockIdx.x * 64;
    int chunk = tid & 15, r0 = tid >> 4;

    for (int it = 0; it < 4; it++) {
        int r = r0 + it * 16;
        int gr = rowBase + r;
        uint4 val = make_uint4(0, 0, 0, 0);
        if (gr < N) val = *(const uint4*)(aggbf + (size_t)gr * 128 + chunk * 8);
        *(uint4*)&As[r * 128 + ((chunk * 8) ^ ((r & 7) << 3))] = val;
    }
    for (int it = 0; it < 8; it++) {
        int r = r0 + it * 16;
        uint4 val = *(const uint4*)(Wpbf + (size_t)r * 128 + chunk * 8);
        *(uint4*)&Bs[r * 128 + ((chunk * 8) ^ ((r & 7) << 3))] = val;
    }
    __syncthreads();

    int w = tid >> 6, l = tid & 63;
    int lr = l & 15, lq = l >> 4;
    bf16x8 a[4];
    int ar = w * 16 + lr;
    for (int kk = 0; kk < 4; kk++)
        a[kk] = *(const bf16x8*)&As[ar * 128 + ((kk * 32 + lq * 8) ^ ((ar & 7) << 3))];

    for (int ct = 0; ct < 8; ct++) {
        int br = ct * 16 + lr;
        f32x4 acc = {0.f, 0.f, 0.f, 0.f};
        for (int kk = 0; kk < 4; kk++) {
            bf16x8 b = *(const bf16x8*)&Bs[br * 128 + ((kk * 32 + lq * 8) ^ ((br & 7) << 3))];
            acc = __builtin_amdgcn_mfma_f32_16x16x32_bf16(a[kk], b, acc, 0, 0, 0);
        }
        int j = ct * 16 + lr;
        float bj = bp[j];
        for (int ri = 0; ri < 4; ri++) {
            int row = rowBase + w * 16 + lq * 4 + ri;
            if (row < N) {
                float val = acc[ri] + bj + h[(size_t)row * 128 + j];
                out[(size_t)row * 128 + j] = fmaxf(val, 0.f);
            }
        }
    }
}

extern "C" void kernel_launch(void* const* d_in, const int* in_sizes, int n_in,
                              void* d_out, int out_size, void* d_ws, size_t ws_size,
                              hipStream_t stream) {
    const float* h  = (const float*)d_in[0];
    const int* edges = (const int*)d_in[1];
    const float* Wq = (const float*)d_in[2];
    const float* Wk = (const float*)d_in[3];
    const float* Wv = (const float*)d_in[4];
    const float* Wp = (const float*)d_in[5];
    const float* bp = (const float*)d_in[6];
    float* out = (float*)d_out;

    int N = in_sizes[0] / 128;
    int E = in_sizes[1] / 2;

    char* ws = (char*)d_ws;
    size_t off = 0;
    auto alloc = [&](size_t bytes) -> char* {
        char* p = ws + off;
        off = (off + bytes + 255) & ~(size_t)255;
        return p;
    };
    u16* hbf  = (u16*)alloc((size_t)N * 128 * 2);
    u16* B1   = (u16*)alloc(256 * 128 * 2);
    u16* Wpbf = (u16*)alloc(128 * 128 * 2);
    u16* g    = (u16*)alloc((size_t)N * 128 * 2);
    u16* v    = (u16*)alloc((size_t)N * 128 * 2);
    u16* agg  = (u16*)alloc((size_t)N * 128 * 2);
    int* deg    = (int*)alloc((size_t)N * 4);
    int* offs   = (int*)alloc((size_t)(N + 1) * 4);
    int* cursor = (int*)alloc((size_t)N * 4);
    int* esrc   = (int*)alloc((size_t)E * 4);
    (void)ws_size; (void)n_in; (void)out_size;

    hipMemsetAsync(deg, 0, (size_t)N * 4, stream);

    int total = N * 128;
    k_conv_h<<<(total / 4 + 255) / 256, 256, 0, stream>>>(h, hbf, total);
    k_prep<<<384, 128, 0, stream>>>(Wq, Wk, Wv, Wp, B1, Wpbf);
    k_hist<<<(E + 255) / 256, 256, 0, stream>>>(edges, deg, E);
    k_scan<<<1, 1024, 0, stream>>>(deg, offs, cursor, N, E);
    k_scatter<<<(E + 255) / 256, 256, 0, stream>>>(edges, cursor, esrc, E);
    k_gemm1<<<(N + 63) / 64, 256, 0, stream>>>(hbf, B1, g, v, N);
    k_edge<<<(N + 3) / 4, 256, 0, stream>>>(g, hbf, v, offs, esrc, agg, N);
    k_gemm2<<<(N + 63) / 64, 256, 0, stream>>>(agg, Wpbf, bp, h, out, N);
}

// Round 5
// 315.961 us; speedup vs baseline: 1.7436x; 1.7436x over previous
//
#include <hip/hip_runtime.h>
#include <hip/hip_bf16.h>

typedef unsigned short u16;
typedef unsigned int u32;
typedef short bf16x8 __attribute__((ext_vector_type(8)));
typedef float f32x4 __attribute__((ext_vector_type(4)));

__device__ __forceinline__ float bf2f(u32 bits16) {
    return __uint_as_float(bits16 << 16);
}
__device__ __forceinline__ u16 f2bf(float f) {
    u32 u = __float_as_uint(f);
    u32 r = (u + 0x7fffu + ((u >> 16) & 1u)) >> 16;   // RNE
    return (u16)r;
}

// ---------------- h (f32) -> hbf (bf16) ----------------
__global__ void k_conv_h(const float* __restrict__ h, u16* __restrict__ hbf, int total) {
    int i = (blockIdx.x * blockDim.x + threadIdx.x) * 4;
    if (i < total) {
        float4 val = *(const float4*)(h + i);
        u32 lo = ((u32)f2bf(val.y) << 16) | f2bf(val.x);
        u32 hi = ((u32)f2bf(val.w) << 16) | f2bf(val.z);
        uint2 o; o.x = lo; o.y = hi;
        *(uint2*)(hbf + i) = o;
    }
}

// ---------------- build B1 = [M^T ; Wv] (256x128 bf16), Wpbf (128x128 bf16) ----
__global__ void k_prep(const float* __restrict__ Wq, const float* __restrict__ Wk,
                       const float* __restrict__ Wv, const float* __restrict__ Wp,
                       u16* __restrict__ B1, u16* __restrict__ Wpbf) {
    int j = blockIdx.x;
    int k = threadIdx.x;  // 128 threads
    if (j < 128) {
        float s = 0.f;
        for (int t = 0; t < 128; t++) s += Wq[t * 128 + k] * Wk[t * 128 + j];
        B1[j * 128 + k] = f2bf(s);
    } else if (j < 256) {
        B1[j * 128 + k] = f2bf(Wv[(j - 128) * 128 + k]);
    } else {
        Wpbf[(j - 256) * 128 + k] = f2bf(Wp[(j - 256) * 128 + k]);
    }
}

// ---------------- degree histogram + per-edge rank ----------------
__global__ void k_hist(const int* __restrict__ edges, int* __restrict__ deg,
                       int* __restrict__ erank, int E) {
    int e = blockIdx.x * blockDim.x + threadIdx.x;
    if (e < E) {
        int dst = edges[E + e];
        erank[e] = atomicAdd(&deg[dst], 1);
    }
}

// ---------------- hierarchical exclusive scan ----------------
// K1: per-block partial sums (1024 deg elements / block, 256 thr x 4)
__global__ void k_scan_part(const int* __restrict__ deg, int* __restrict__ bsum, int N) {
    __shared__ int red[256];
    int b = blockIdx.x, t = threadIdx.x;
    int i0 = b * 1024 + t * 4;
    int s = 0;
    if (i0 + 3 < N) {
        int4 v = *(const int4*)(deg + i0);
        s = v.x + v.y + v.z + v.w;
    } else {
        for (int k = 0; k < 4; k++) if (i0 + k < N) s += deg[i0 + k];
    }
    red[t] = s;
    __syncthreads();
    for (int off = 128; off > 0; off >>= 1) {
        if (t < off) red[t] += red[t + off];
        __syncthreads();
    }
    if (t == 0) bsum[b] = red[0];
}

// K2: scan the block sums (NB <= 256), in-place exclusive; offs[N] = total
__global__ void k_scan_top(int* __restrict__ bsum, int* __restrict__ offs, int NB, int N) {
    __shared__ int tmp[256];
    int t = threadIdx.x;
    int v = (t < NB) ? bsum[t] : 0;
    tmp[t] = v;
    __syncthreads();
    for (int off = 1; off < 256; off <<= 1) {
        int cur = tmp[t];
        int a = (t >= off) ? tmp[t - off] : 0;
        __syncthreads();
        tmp[t] = cur + a;
        __syncthreads();
    }
    if (t < NB) bsum[t] = tmp[t] - v;   // exclusive
    if (t == 255) offs[N] = tmp[255];   // total = E
}

// K3: per-block local scan + block base -> offs
__global__ void k_scan_down(const int* __restrict__ deg, const int* __restrict__ bsum,
                            int* __restrict__ offs, int N) {
    __shared__ int tmp[256];
    int b = blockIdx.x, t = threadIdx.x;
    int i0 = b * 1024 + t * 4;
    int d0 = 0, d1 = 0, d2 = 0, d3 = 0;
    if (i0 + 3 < N) {
        int4 v = *(const int4*)(deg + i0);
        d0 = v.x; d1 = v.y; d2 = v.z; d3 = v.w;
    } else {
        if (i0 < N)     d0 = deg[i0];
        if (i0 + 1 < N) d1 = deg[i0 + 1];
        if (i0 + 2 < N) d2 = deg[i0 + 2];
        if (i0 + 3 < N) d3 = deg[i0 + 3];
    }
    int s = d0 + d1 + d2 + d3;
    tmp[t] = s;
    __syncthreads();
    for (int off = 1; off < 256; off <<= 1) {
        int cur = tmp[t];
        int a = (t >= off) ? tmp[t - off] : 0;
        __syncthreads();
        tmp[t] = cur + a;
        __syncthreads();
    }
    int run = bsum[b] + tmp[t] - s;   // exclusive prefix for this thread's 4
    if (i0 < N)     offs[i0]     = run; run += d0;
    if (i0 + 1 < N) offs[i0 + 1] = run; run += d1;
    if (i0 + 2 < N) offs[i0 + 2] = run; run += d2;
    if (i0 + 3 < N) offs[i0 + 3] = run;
}

// ---------------- scatter edge srcs into CSR (no atomics; uses erank) --------
__global__ void k_scatter(const int* __restrict__ edges, const int* __restrict__ offs,
                          const int* __restrict__ erank, int* __restrict__ esrc, int E) {
    int e = blockIdx.x * blockDim.x + threadIdx.x;
    if (e < E) {
        int dst = edges[E + e];
        esrc[offs[dst] + erank[e]] = edges[e];
    }
}

// ---------------- GEMM1: [g|v] = hbf @ B1^T  (out bf16) ----------------
__launch_bounds__(256)
__global__ void k_gemm1(const u16* __restrict__ hbf, const u16* __restrict__ B1,
                        u16* __restrict__ g, u16* __restrict__ v, int N) {
    __shared__ u16 As[64 * 128];    // 16 KB, swizzled
    __shared__ u16 Bs[128 * 128];   // 32 KB, swizzled
    int tid = threadIdx.x;
    int rowBase = blockIdx.x * 64;
    int chunk = tid & 15, r0 = tid >> 4;

    for (int it = 0; it < 4; it++) {
        int r = r0 + it * 16;
        int gr = rowBase + r;
        uint4 val = make_uint4(0, 0, 0, 0);
        if (gr < N) val = *(const uint4*)(hbf + (size_t)gr * 128 + chunk * 8);
        *(uint4*)&As[r * 128 + ((chunk * 8) ^ ((r & 7) << 3))] = val;
    }

    int w = tid >> 6, l = tid & 63;
    int lr = l & 15, lq = l >> 4;

    for (int half = 0; half < 2; half++) {
        if (half) __syncthreads();  // all waves done reading Bs half 0
        for (int it = 0; it < 8; it++) {
            int r = r0 + it * 16;
            uint4 val = *(const uint4*)(B1 + (size_t)(half * 128 + r) * 128 + chunk * 8);
            *(uint4*)&Bs[r * 128 + ((chunk * 8) ^ ((r & 7) << 3))] = val;
        }
        __syncthreads();

        bf16x8 a[4];
        int ar = w * 16 + lr;
        for (int kk = 0; kk < 4; kk++)
            a[kk] = *(const bf16x8*)&As[ar * 128 + ((kk * 32 + lq * 8) ^ ((ar & 7) << 3))];

        for (int ct = 0; ct < 8; ct++) {
            int br = ct * 16 + lr;
            f32x4 acc = {0.f, 0.f, 0.f, 0.f};
            for (int kk = 0; kk < 4; kk++) {
                bf16x8 b = *(const bf16x8*)&Bs[br * 128 + ((kk * 32 + lq * 8) ^ ((br & 7) << 3))];
                acc = __builtin_amdgcn_mfma_f32_16x16x32_bf16(a[kk], b, acc, 0, 0, 0);
            }
            int j = ct * 16 + lr;  // col within this half
            for (int ri = 0; ri < 4; ri++) {
                int row = rowBase + w * 16 + lq * 4 + ri;
                if (row < N) {
                    u16 bv = f2bf(acc[ri]);
                    if (half == 0) g[(size_t)row * 128 + j] = bv;
                    else           v[(size_t)row * 128 + j] = bv;
                }
            }
        }
    }
}

// ---------------- fused edge kernel: one wave per dst node ----------------
__launch_bounds__(256)
__global__ void k_edge(const u16* __restrict__ g, const u16* __restrict__ hbf,
                       const u16* __restrict__ vbf, const int* __restrict__ offs,
                       const int* __restrict__ esrc, u16* __restrict__ agg, int N) {
    int wid = (blockIdx.x * blockDim.x + threadIdx.x) >> 6;
    int lane = threadIdx.x & 63;
    if (wid >= N) return;
    const u32* g32 = (const u32*)g;
    const u32* h32 = (const u32*)hbf;
    const u32* v32 = (const u32*)vbf;
    u32 gv = g32[(size_t)wid * 64 + lane];
    float g0 = bf2f(gv & 0xffff), g1 = bf2f(gv >> 16);
    int e0 = offs[wid], e1 = offs[wid + 1];
    float acc0 = 0.f, acc1 = 0.f, denom = 0.f;
    const float sc = 0.08838834764831845f;  // 1/sqrt(128)
    for (int i = e0; i < e1; i++) {
        int src = esrc[i];
        u32 hv = h32[(size_t)src * 64 + lane];
        float p = g0 * bf2f(hv & 0xffff) + g1 * bf2f(hv >> 16);
        for (int m = 1; m < 64; m <<= 1) p += __shfl_xor(p, m, 64);
        float ew = __expf(p * sc);
        denom += ew;
        u32 vv = v32[(size_t)src * 64 + lane];
        acc0 += ew * bf2f(vv & 0xffff);
        acc1 += ew * bf2f(vv >> 16);
    }
    float inv = (denom > 0.f) ? 1.f / denom : 0.f;
    u32 o = ((u32)f2bf(acc1 * inv) << 16) | f2bf(acc0 * inv);
    ((u32*)agg)[(size_t)wid * 64 + lane] = o;
}

// ---------------- GEMM2: out = relu(agg @ Wp^T + bp + h)  (f32 out) ----------
__launch_bounds__(256)
__global__ void k_gemm2(const u16* __restrict__ aggbf, const u16* __restrict__ Wpbf,
                        const float* __restrict__ bp, const float* __restrict__ h,
                        float* __restrict__ out, int N) {
    __shared__ u16 As[64 * 128];    // 16 KB
    __shared__ u16 Bs[128 * 128];   // 32 KB
    int tid = threadIdx.x;
    int rowBase = blockIdx.x * 64;
    int chunk = tid & 15, r0 = tid >> 4;

    for (int it = 0; it < 4; it++) {
        int r = r0 + it * 16;
        int gr = rowBase + r;
        uint4 val = make_uint4(0, 0, 0, 0);
        if (gr < N) val = *(const uint4*)(aggbf + (size_t)gr * 128 + chunk * 8);
        *(uint4*)&As[r * 128 + ((chunk * 8) ^ ((r & 7) << 3))] = val;
    }
    for (int it = 0; it < 8; it++) {
        int r = r0 + it * 16;
        uint4 val = *(const uint4*)(Wpbf + (size_t)r * 128 + chunk * 8);
        *(uint4*)&Bs[r * 128 + ((chunk * 8) ^ ((r & 7) << 3))] = val;
    }
    __syncthreads();

    int w = tid >> 6, l = tid & 63;
    int lr = l & 15, lq = l >> 4;
    bf16x8 a[4];
    int ar = w * 16 + lr;
    for (int kk = 0; kk < 4; kk++)
        a[kk] = *(const bf16x8*)&As[ar * 128 + ((kk * 32 + lq * 8) ^ ((ar & 7) << 3))];

    for (int ct = 0; ct < 8; ct++) {
        int br = ct * 16 + lr;
        f32x4 acc = {0.f, 0.f, 0.f, 0.f};
        for (int kk = 0; kk < 4; kk++) {
            bf16x8 b = *(const bf16x8*)&Bs[br * 128 + ((kk * 32 + lq * 8) ^ ((br & 7) << 3))];
            acc = __builtin_amdgcn_mfma_f32_16x16x32_bf16(a[kk], b, acc, 0, 0, 0);
        }
        int j = ct * 16 + lr;
        float bj = bp[j];
        for (int ri = 0; ri < 4; ri++) {
            int row = rowBase + w * 16 + lq * 4 + ri;
            if (row < N) {
                float val = acc[ri] + bj + h[(size_t)row * 128 + j];
                out[(size_t)row * 128 + j] = fmaxf(val, 0.f);
            }
        }
    }
}

extern "C" void kernel_launch(void* const* d_in, const int* in_sizes, int n_in,
                              void* d_out, int out_size, void* d_ws, size_t ws_size,
                              hipStream_t stream) {
    const float* h  = (const float*)d_in[0];
    const int* edges = (const int*)d_in[1];
    const float* Wq = (const float*)d_in[2];
    const float* Wk = (const float*)d_in[3];
    const float* Wv = (const float*)d_in[4];
    const float* Wp = (const float*)d_in[5];
    const float* bp = (const float*)d_in[6];
    float* out = (float*)d_out;

    int N = in_sizes[0] / 128;
    int E = in_sizes[1] / 2;

    char* ws = (char*)d_ws;
    size_t off = 0;
    auto alloc = [&](size_t bytes) -> char* {
        char* p = ws + off;
        off = (off + bytes + 255) & ~(size_t)255;
        return p;
    };
    u16* hbf  = (u16*)alloc((size_t)N * 128 * 2);
    u16* B1   = (u16*)alloc(256 * 128 * 2);
    u16* Wpbf = (u16*)alloc(128 * 128 * 2);
    u16* g    = (u16*)alloc((size_t)N * 128 * 2);
    u16* v    = (u16*)alloc((size_t)N * 128 * 2);
    u16* agg  = (u16*)alloc((size_t)N * 128 * 2);
    int* deg   = (int*)alloc((size_t)N * 4);
    int* offs  = (int*)alloc((size_t)(N + 1) * 4);
    int* erank = (int*)alloc((size_t)E * 4);
    int* esrc  = (int*)alloc((size_t)E * 4);
    int* bsum  = (int*)alloc(256 * 4);
    (void)ws_size; (void)n_in; (void)out_size;

    hipMemsetAsync(deg, 0, (size_t)N * 4, stream);

    int NB = (N + 1023) / 1024;   // 98 for N=100k (<=256 supported)
    int total = N * 128;
    k_conv_h<<<(total / 4 + 255) / 256, 256, 0, stream>>>(h, hbf, total);
    k_prep<<<384, 128, 0, stream>>>(Wq, Wk, Wv, Wp, B1, Wpbf);
    k_hist<<<(E + 255) / 256, 256, 0, stream>>>(edges, deg, erank, E);
    k_scan_part<<<NB, 256, 0, stream>>>(deg, bsum, N);
    k_scan_top<<<1, 256, 0, stream>>>(bsum, offs, NB, N);
    k_scan_down<<<NB, 256, 0, stream>>>(deg, bsum, offs, N);
    k_scatter<<<(E + 255) / 256, 256, 0, stream>>>(edges, offs, erank, esrc, E);
    k_gemm1<<<(N + 63) / 64, 256, 0, stream>>>(hbf, B1, g, v, N);
    k_edge<<<(N + 3) / 4, 256, 0, stream>>>(g, hbf, v, offs, esrc, agg, N);
    k_gemm2<<<(N + 63) / 64, 256, 0, stream>>>(agg, Wpbf, bp, h, out, N);
}

// Round 6
// 278.274 us; speedup vs baseline: 1.9797x; 1.1354x over previous
//
#include <hip/hip_runtime.h>
#include <hip/hip_bf16.h>

typedef unsigned short u16;
typedef unsigned int u32;
typedef short bf16x8 __attribute__((ext_vector_type(8)));
typedef float f32x4 __attribute__((ext_vector_type(4)));

__device__ __forceinline__ float bf2f(u32 bits16) {
    return __uint_as_float(bits16 << 16);
}
__device__ __forceinline__ u16 f2bf(float f) {
    u32 u = __float_as_uint(f);
    u32 r = (u + 0x7fffu + ((u >> 16) & 1u)) >> 16;   // RNE
    return (u16)r;
}

// ---------------- h (f32) -> hbf (bf16) ----------------
__global__ void k_conv_h(const float* __restrict__ h, u16* __restrict__ hbf, int total) {
    int i = (blockIdx.x * blockDim.x + threadIdx.x) * 4;
    if (i < total) {
        float4 val = *(const float4*)(h + i);
        u32 lo = ((u32)f2bf(val.y) << 16) | f2bf(val.x);
        u32 hi = ((u32)f2bf(val.w) << 16) | f2bf(val.z);
        uint2 o; o.x = lo; o.y = hi;
        *(uint2*)(hbf + i) = o;
    }
}

// ---------------- build B1 = [M^T ; Wv] (256x128 bf16), Wpbf (128x128 bf16) ----
__global__ void k_prep(const float* __restrict__ Wq, const float* __restrict__ Wk,
                       const float* __restrict__ Wv, const float* __restrict__ Wp,
                       u16* __restrict__ B1, u16* __restrict__ Wpbf) {
    int j = blockIdx.x;
    int k = threadIdx.x;  // 128 threads
    if (j < 128) {
        float s = 0.f;
        for (int t = 0; t < 128; t++) s += Wq[t * 128 + k] * Wk[t * 128 + j];
        B1[j * 128 + k] = f2bf(s);
    } else if (j < 256) {
        B1[j * 128 + k] = f2bf(Wv[(j - 128) * 128 + k]);
    } else {
        Wpbf[(j - 256) * 128 + k] = f2bf(Wp[(j - 256) * 128 + k]);
    }
}

// ---------------- degree histogram + per-edge rank ----------------
__global__ void k_hist(const int* __restrict__ edges, int* __restrict__ deg,
                       int* __restrict__ erank, int E) {
    int e = blockIdx.x * blockDim.x + threadIdx.x;
    if (e < E) {
        int dst = edges[E + e];
        erank[e] = atomicAdd(&deg[dst], 1);
    }
}

// ---------------- hierarchical exclusive scan ----------------
__global__ void k_scan_part(const int* __restrict__ deg, int* __restrict__ bsum, int N) {
    __shared__ int red[256];
    int b = blockIdx.x, t = threadIdx.x;
    int i0 = b * 1024 + t * 4;
    int s = 0;
    if (i0 + 3 < N) {
        int4 v = *(const int4*)(deg + i0);
        s = v.x + v.y + v.z + v.w;
    } else {
        for (int k = 0; k < 4; k++) if (i0 + k < N) s += deg[i0 + k];
    }
    red[t] = s;
    __syncthreads();
    for (int off = 128; off > 0; off >>= 1) {
        if (t < off) red[t] += red[t + off];
        __syncthreads();
    }
    if (t == 0) bsum[b] = red[0];
}

__global__ void k_scan_top(int* __restrict__ bsum, int* __restrict__ offs, int NB, int N) {
    __shared__ int tmp[256];
    int t = threadIdx.x;
    int v = (t < NB) ? bsum[t] : 0;
    tmp[t] = v;
    __syncthreads();
    for (int off = 1; off < 256; off <<= 1) {
        int cur = tmp[t];
        int a = (t >= off) ? tmp[t - off] : 0;
        __syncthreads();
        tmp[t] = cur + a;
        __syncthreads();
    }
    if (t < NB) bsum[t] = tmp[t] - v;   // exclusive
    if (t == 255) offs[N] = tmp[255];   // total = E
}

__global__ void k_scan_down(const int* __restrict__ deg, const int* __restrict__ bsum,
                            int* __restrict__ offs, int N) {
    __shared__ int tmp[256];
    int b = blockIdx.x, t = threadIdx.x;
    int i0 = b * 1024 + t * 4;
    int d0 = 0, d1 = 0, d2 = 0, d3 = 0;
    if (i0 + 3 < N) {
        int4 v = *(const int4*)(deg + i0);
        d0 = v.x; d1 = v.y; d2 = v.z; d3 = v.w;
    } else {
        if (i0 < N)     d0 = deg[i0];
        if (i0 + 1 < N) d1 = deg[i0 + 1];
        if (i0 + 2 < N) d2 = deg[i0 + 2];
        if (i0 + 3 < N) d3 = deg[i0 + 3];
    }
    int s = d0 + d1 + d2 + d3;
    tmp[t] = s;
    __syncthreads();
    for (int off = 1; off < 256; off <<= 1) {
        int cur = tmp[t];
        int a = (t >= off) ? tmp[t - off] : 0;
        __syncthreads();
        tmp[t] = cur + a;
        __syncthreads();
    }
    int run = bsum[b] + tmp[t] - s;   // exclusive prefix for this thread's 4
    if (i0 < N)     offs[i0]     = run; run += d0;
    if (i0 + 1 < N) offs[i0 + 1] = run; run += d1;
    if (i0 + 2 < N) offs[i0 + 2] = run; run += d2;
    if (i0 + 3 < N) offs[i0 + 3] = run;
}

// ---------------- scatter edge srcs into CSR (no atomics; uses erank) --------
__global__ void k_scatter(const int* __restrict__ edges, const int* __restrict__ offs,
                          const int* __restrict__ erank, int* __restrict__ esrc, int E) {
    int e = blockIdx.x * blockDim.x + threadIdx.x;
    if (e < E) {
        int dst = edges[E + e];
        esrc[offs[dst] + erank[e]] = edges[e];
    }
}

// ---------------- GEMM1: [g|v] = hbf @ B1^T  (out bf16) ----------------
__launch_bounds__(256)
__global__ void k_gemm1(const u16* __restrict__ hbf, const u16* __restrict__ B1,
                        u16* __restrict__ g, u16* __restrict__ v, int N) {
    __shared__ u16 As[64 * 128];    // 16 KB, swizzled
    __shared__ u16 Bs[128 * 128];   // 32 KB, swizzled
    int tid = threadIdx.x;
    int rowBase = blockIdx.x * 64;
    int chunk = tid & 15, r0 = tid >> 4;

    for (int it = 0; it < 4; it++) {
        int r = r0 + it * 16;
        int gr = rowBase + r;
        uint4 val = make_uint4(0, 0, 0, 0);
        if (gr < N) val = *(const uint4*)(hbf + (size_t)gr * 128 + chunk * 8);
        *(uint4*)&As[r * 128 + ((chunk * 8) ^ ((r & 7) << 3))] = val;
    }

    int w = tid >> 6, l = tid & 63;
    int lr = l & 15, lq = l >> 4;

    for (int half = 0; half < 2; half++) {
        if (half) __syncthreads();  // all waves done reading Bs half 0
        for (int it = 0; it < 8; it++) {
            int r = r0 + it * 16;
            uint4 val = *(const uint4*)(B1 + (size_t)(half * 128 + r) * 128 + chunk * 8);
            *(uint4*)&Bs[r * 128 + ((chunk * 8) ^ ((r & 7) << 3))] = val;
        }
        __syncthreads();

        bf16x8 a[4];
        int ar = w * 16 + lr;
        for (int kk = 0; kk < 4; kk++)
            a[kk] = *(const bf16x8*)&As[ar * 128 + ((kk * 32 + lq * 8) ^ ((ar & 7) << 3))];

        for (int ct = 0; ct < 8; ct++) {
            int br = ct * 16 + lr;
            f32x4 acc = {0.f, 0.f, 0.f, 0.f};
            for (int kk = 0; kk < 4; kk++) {
                bf16x8 b = *(const bf16x8*)&Bs[br * 128 + ((kk * 32 + lq * 8) ^ ((br & 7) << 3))];
                acc = __builtin_amdgcn_mfma_f32_16x16x32_bf16(a[kk], b, acc, 0, 0, 0);
            }
            int j = ct * 16 + lr;  // col within this half
            for (int ri = 0; ri < 4; ri++) {
                int row = rowBase + w * 16 + lq * 4 + ri;
                if (row < N) {
                    u16 bv = f2bf(acc[ri]);
                    if (half == 0) g[(size_t)row * 128 + j] = bv;
                    else           v[(size_t)row * 128 + j] = bv;
                }
            }
        }
    }
}

// ---------------- fused edge kernel: one wave per dst, 4 edges/iter ----------
// 16-lane group per edge; each lane covers 8 elems (uint4) of the 128-elem row.
__launch_bounds__(256)
__global__ void k_edge(const u16* __restrict__ g, const u16* __restrict__ hbf,
                       const u16* __restrict__ vbf, const int* __restrict__ offs,
                       const int* __restrict__ esrc, u16* __restrict__ agg, int N) {
    int wid = (blockIdx.x * blockDim.x + threadIdx.x) >> 6;
    int lane = threadIdx.x & 63;
    if (wid >= N) return;
    int sub = lane >> 4;    // edge slot 0..3
    int sl  = lane & 15;    // lane within group; covers u32s [sl*4, sl*4+4)
    const uint4* g16 = (const uint4*)g;
    const uint4* h16 = (const uint4*)hbf;
    const uint4* v16 = (const uint4*)vbf;

    uint4 gv = g16[(size_t)wid * 16 + sl];
    float gf0 = bf2f(gv.x & 0xffff), gf1 = bf2f(gv.x >> 16);
    float gf2 = bf2f(gv.y & 0xffff), gf3 = bf2f(gv.y >> 16);
    float gf4 = bf2f(gv.z & 0xffff), gf5 = bf2f(gv.z >> 16);
    float gf6 = bf2f(gv.w & 0xffff), gf7 = bf2f(gv.w >> 16);

    int e0 = offs[wid], e1 = offs[wid + 1];
    float acc[8] = {0.f, 0.f, 0.f, 0.f, 0.f, 0.f, 0.f, 0.f};
    float denom = 0.f;
    const float sc = 0.08838834764831845f;  // 1/sqrt(128)

    for (int base = e0; base < e1; base += 4) {
        int i = base + sub;
        bool act = (i < e1);
        int src = act ? esrc[i] : 0;
        uint4 hv = h16[(size_t)src * 16 + sl];
        float p;
        p  = gf0 * bf2f(hv.x & 0xffff) + gf1 * bf2f(hv.x >> 16);
        p += gf2 * bf2f(hv.y & 0xffff) + gf3 * bf2f(hv.y >> 16);
        p += gf4 * bf2f(hv.z & 0xffff) + gf5 * bf2f(hv.z >> 16);
        p += gf6 * bf2f(hv.w & 0xffff) + gf7 * bf2f(hv.w >> 16);
        p += __shfl_xor(p, 1, 64);
        p += __shfl_xor(p, 2, 64);
        p += __shfl_xor(p, 4, 64);
        p += __shfl_xor(p, 8, 64);
        float ew = act ? __expf(p * sc) : 0.f;
        denom += ew;
        uint4 vv = v16[(size_t)src * 16 + sl];
        acc[0] += ew * bf2f(vv.x & 0xffff); acc[1] += ew * bf2f(vv.x >> 16);
        acc[2] += ew * bf2f(vv.y & 0xffff); acc[3] += ew * bf2f(vv.y >> 16);
        acc[4] += ew * bf2f(vv.z & 0xffff); acc[5] += ew * bf2f(vv.z >> 16);
        acc[6] += ew * bf2f(vv.w & 0xffff); acc[7] += ew * bf2f(vv.w >> 16);
    }

    // cross-group reduce (groups hold same element positions)
    for (int m = 16; m < 64; m <<= 1) {
        denom += __shfl_xor(denom, m, 64);
        for (int k = 0; k < 8; k++) acc[k] += __shfl_xor(acc[k], m, 64);
    }

    if (sub == 0) {
        float inv = (denom > 0.f) ? 1.f / denom : 0.f;
        uint4 o;
        o.x = ((u32)f2bf(acc[1] * inv) << 16) | f2bf(acc[0] * inv);
        o.y = ((u32)f2bf(acc[3] * inv) << 16) | f2bf(acc[2] * inv);
        o.z = ((u32)f2bf(acc[5] * inv) << 16) | f2bf(acc[4] * inv);
        o.w = ((u32)f2bf(acc[7] * inv) << 16) | f2bf(acc[6] * inv);
        ((uint4*)agg)[(size_t)wid * 16 + sl] = o;
    }
}

// ---------------- GEMM2: out = relu(agg @ Wp^T + bp + h)  (f32 out) ----------
__launch_bounds__(256)
__global__ void k_gemm2(const u16* __restrict__ aggbf, const u16* __restrict__ Wpbf,
                        const float* __restrict__ bp, const float* __restrict__ h,
                        float* __restrict__ out, int N) {
    __shared__ u16 As[64 * 128];    // 16 KB
    __shared__ u16 Bs[128 * 128];   // 32 KB
    int tid = threadIdx.x;
    int rowBase = blockIdx.x * 64;
    int chunk = tid & 15, r0 = tid >> 4;

    for (int it = 0; it < 4; it++) {
        int r = r0 + it * 16;
        int gr = rowBase + r;
        uint4 val = make_uint4(0, 0, 0, 0);
        if (gr < N) val = *(const uint4*)(aggbf + (size_t)gr * 128 + chunk * 8);
        *(uint4*)&As[r * 128 + ((chunk * 8) ^ ((r & 7) << 3))] = val;
    }
    for (int it = 0; it < 8; it++) {
        int r = r0 + it * 16;
        uint4 val = *(const uint4*)(Wpbf + (size_t)r * 128 + chunk * 8);
        *(uint4*)&Bs[r * 128 + ((chunk * 8) ^ ((r & 7) << 3))] = val;
    }
    __syncthreads();

    int w = tid >> 6, l = tid & 63;
    int lr = l & 15, lq = l >> 4;
    bf16x8 a[4];
    int ar = w * 16 + lr;
    for (int kk = 0; kk < 4; kk++)
        a[kk] = *(const bf16x8*)&As[ar * 128 + ((kk * 32 + lq * 8) ^ ((ar & 7) << 3))];

    for (int ct = 0; ct < 8; ct++) {
        int br = ct * 16 + lr;
        f32x4 acc = {0.f, 0.f, 0.f, 0.f};
        for (int kk = 0; kk < 4; kk++) {
            bf16x8 b = *(const bf16x8*)&Bs[br * 128 + ((kk * 32 + lq * 8) ^ ((br & 7) << 3))];
            acc = __builtin_amdgcn_mfma_f32_16x16x32_bf16(a[kk], b, acc, 0, 0, 0);
        }
        int j = ct * 16 + lr;
        float bj = bp[j];
        for (int ri = 0; ri < 4; ri++) {
            int row = rowBase + w * 16 + lq * 4 + ri;
            if (row < N) {
                float val = acc[ri] + bj + h[(size_t)row * 128 + j];
                out[(size_t)row * 128 + j] = fmaxf(val, 0.f);
            }
        }
    }
}

extern "C" void kernel_launch(void* const* d_in, const int* in_sizes, int n_in,
                              void* d_out, int out_size, void* d_ws, size_t ws_size,
                              hipStream_t stream) {
    const float* h  = (const float*)d_in[0];
    const int* edges = (const int*)d_in[1];
    const float* Wq = (const float*)d_in[2];
    const float* Wk = (const float*)d_in[3];
    const float* Wv = (const float*)d_in[4];
    const float* Wp = (const float*)d_in[5];
    const float* bp = (const float*)d_in[6];
    float* out = (float*)d_out;

    int N = in_sizes[0] / 128;
    int E = in_sizes[1] / 2;

    char* ws = (char*)d_ws;
    size_t off = 0;
    auto alloc = [&](size_t bytes) -> char* {
        char* p = ws + off;
        off = (off + bytes + 255) & ~(size_t)255;
        return p;
    };
    u16* hbf  = (u16*)alloc((size_t)N * 128 * 2);
    u16* B1   = (u16*)alloc(256 * 128 * 2);
    u16* Wpbf = (u16*)alloc(128 * 128 * 2);
    u16* g    = (u16*)alloc((size_t)N * 128 * 2);
    u16* v    = (u16*)alloc((size_t)N * 128 * 2);
    u16* agg  = (u16*)alloc((size_t)N * 128 * 2);
    int* deg   = (int*)alloc((size_t)N * 4);
    int* offs  = (int*)alloc((size_t)(N + 1) * 4);
    int* erank = (int*)alloc((size_t)E * 4);
    int* esrc  = (int*)alloc((size_t)E * 4);
    int* bsum  = (int*)alloc(256 * 4);
    (void)ws_size; (void)n_in; (void)out_size;

    hipMemsetAsync(deg, 0, (size_t)N * 4, stream);

    int NB = (N + 1023) / 1024;   // 98 for N=100k (<=256 supported)
    int total = N * 128;
    k_conv_h<<<(total / 4 + 255) / 256, 256, 0, stream>>>(h, hbf, total);
    k_prep<<<384, 128, 0, stream>>>(Wq, Wk, Wv, Wp, B1, Wpbf);
    k_hist<<<(E + 255) / 256, 256, 0, stream>>>(edges, deg, erank, E);
    k_scan_part<<<NB, 256, 0, stream>>>(deg, bsum, N);
    k_scan_top<<<1, 256, 0, stream>>>(bsum, offs, NB, N);
    k_scan_down<<<NB, 256, 0, stream>>>(deg, bsum, offs, N);
    k_scatter<<<(E + 255) / 256, 256, 0, stream>>>(edges, offs, erank, esrc, E);
    k_gemm1<<<(N + 63) / 64, 256, 0, stream>>>(hbf, B1, g, v, N);
    k_edge<<<(N + 3) / 4, 256, 0, stream>>>(g, hbf, v, offs, esrc, agg, N);
    k_gemm2<<<(N + 63) / 64, 256, 0, stream>>>(agg, Wpbf, bp, h, out, N);
}

// Round 9
// 253.795 us; speedup vs baseline: 2.1707x; 1.0965x over previous
//
#include <hip/hip_runtime.h>
#include <hip/hip_bf16.h>

typedef unsigned short u16;
typedef unsigned int u32;
typedef short bf16x8 __attribute__((ext_vector_type(8)));
typedef float f32x4 __attribute__((ext_vector_type(4)));

__device__ __forceinline__ float bf2f(u32 bits16) {
    return __uint_as_float(bits16 << 16);
}
__device__ __forceinline__ u16 f2bf(float f) {
    u32 u = __float_as_uint(f);
    u32 r = (u + 0x7fffu + ((u >> 16) & 1u)) >> 16;   // RNE
    return (u16)r;
}

// ---------------- h (f32) -> hbf (bf16) ----------------
__global__ void k_conv_h(const float* __restrict__ h, u16* __restrict__ hbf, int total) {
    int i = (blockIdx.x * blockDim.x + threadIdx.x) * 4;
    if (i < total) {
        float4 val = *(const float4*)(h + i);
        u32 lo = ((u32)f2bf(val.y) << 16) | f2bf(val.x);
        u32 hi = ((u32)f2bf(val.w) << 16) | f2bf(val.z);
        uint2 o; o.x = lo; o.y = hi;
        *(uint2*)(hbf + i) = o;
    }
}

// ---------------- build B1 = M^T = (Wq^T Wk)^T rows (128x128 bf16),
//                  Wpv = Wp @ Wv (128x128 bf16) ----------------
// B1[j][k]  = sum_t Wq[t][k]*Wk[t][j]   => g = hbf @ B1^T gives g[n]j = h^T Wq^T Wk
// Wpv[m][k] = sum_t Wp[m][t]*Wv[t][k]   => out = agg_h @ Wpv^T  (Wv folded into Wp)
__global__ void k_prep(const float* __restrict__ Wq, const float* __restrict__ Wk,
                       const float* __restrict__ Wv, const float* __restrict__ Wp,
                       u16* __restrict__ B1, u16* __restrict__ Wpv) {
    int j = blockIdx.x;
    int k = threadIdx.x;  // 128 threads
    if (j < 128) {
        float s = 0.f;
        for (int t = 0; t < 128; t++) s += Wq[t * 128 + k] * Wk[t * 128 + j];
        B1[j * 128 + k] = f2bf(s);
    } else {
        int m = j - 128;
        float s = 0.f;
        for (int t = 0; t < 128; t++) s += Wp[m * 128 + t] * Wv[t * 128 + k];
        Wpv[m * 128 + k] = f2bf(s);
    }
}

// ---------------- degree histogram + per-edge rank ----------------
__global__ void k_hist(const int* __restrict__ edges, int* __restrict__ deg,
                       int* __restrict__ erank, int E) {
    int e = blockIdx.x * blockDim.x + threadIdx.x;
    if (e < E) {
        int dst = edges[E + e];
        erank[e] = atomicAdd(&deg[dst], 1);
    }
}

// ---------------- hierarchical exclusive scan ----------------
__global__ void k_scan_part(const int* __restrict__ deg, int* __restrict__ bsum, int N) {
    __shared__ int red[256];
    int b = blockIdx.x, t = threadIdx.x;
    int i0 = b * 1024 + t * 4;
    int s = 0;
    if (i0 + 3 < N) {
        int4 v = *(const int4*)(deg + i0);
        s = v.x + v.y + v.z + v.w;
    } else {
        for (int k = 0; k < 4; k++) if (i0 + k < N) s += deg[i0 + k];
    }
    red[t] = s;
    __syncthreads();
    for (int off = 128; off > 0; off >>= 1) {
        if (t < off) red[t] += red[t + off];
        __syncthreads();
    }
    if (t == 0) bsum[b] = red[0];
}

__global__ void k_scan_top(int* __restrict__ bsum, int* __restrict__ offs, int NB, int N) {
    __shared__ int tmp[256];
    int t = threadIdx.x;
    int v = (t < NB) ? bsum[t] : 0;
    tmp[t] = v;
    __syncthreads();
    for (int off = 1; off < 256; off <<= 1) {
        int cur = tmp[t];
        int a = (t >= off) ? tmp[t - off] : 0;
        __syncthreads();
        tmp[t] = cur + a;
        __syncthreads();
    }
    if (t < NB) bsum[t] = tmp[t] - v;   // exclusive
    if (t == 255) offs[N] = tmp[255];   // total = E
}

__global__ void k_scan_down(const int* __restrict__ deg, const int* __restrict__ bsum,
                            int* __restrict__ offs, int N) {
    __shared__ int tmp[256];
    int b = blockIdx.x, t = threadIdx.x;
    int i0 = b * 1024 + t * 4;
    int d0 = 0, d1 = 0, d2 = 0, d3 = 0;
    if (i0 + 3 < N) {
        int4 v = *(const int4*)(deg + i0);
        d0 = v.x; d1 = v.y; d2 = v.z; d3 = v.w;
    } else {
        if (i0 < N)     d0 = deg[i0];
        if (i0 + 1 < N) d1 = deg[i0 + 1];
        if (i0 + 2 < N) d2 = deg[i0 + 2];
        if (i0 + 3 < N) d3 = deg[i0 + 3];
    }
    int s = d0 + d1 + d2 + d3;
    tmp[t] = s;
    __syncthreads();
    for (int off = 1; off < 256; off <<= 1) {
        int cur = tmp[t];
        int a = (t >= off) ? tmp[t - off] : 0;
        __syncthreads();
        tmp[t] = cur + a;
        __syncthreads();
    }
    int run = bsum[b] + tmp[t] - s;   // exclusive prefix for this thread's 4
    if (i0 < N)     offs[i0]     = run; run += d0;
    if (i0 + 1 < N) offs[i0 + 1] = run; run += d1;
    if (i0 + 2 < N) offs[i0 + 2] = run; run += d2;
    if (i0 + 3 < N) offs[i0 + 3] = run;
}

// ---------------- scatter edge srcs into CSR (no atomics; uses erank) --------
__global__ void k_scatter(const int* __restrict__ edges, const int* __restrict__ offs,
                          const int* __restrict__ erank, int* __restrict__ esrc, int E) {
    int e = blockIdx.x * blockDim.x + threadIdx.x;
    if (e < E) {
        int dst = edges[E + e];
        esrc[offs[dst] + erank[e]] = edges[e];
    }
}

// ---------------- GEMM1: g = hbf @ B1^T  (out bf16, 128 cols) ----------------
__launch_bounds__(256)
__global__ void k_gemm1(const u16* __restrict__ hbf, const u16* __restrict__ B1,
                        u16* __restrict__ g, int N) {
    __shared__ u16 As[64 * 128];    // 16 KB, swizzled
    __shared__ u16 Bs[128 * 128];   // 32 KB, swizzled
    int tid = threadIdx.x;
    int rowBase = blockIdx.x * 64;
    int chunk = tid & 15, r0 = tid >> 4;

    for (int it = 0; it < 4; it++) {
        int r = r0 + it * 16;
        int gr = rowBase + r;
        uint4 val = make_uint4(0, 0, 0, 0);
        if (gr < N) val = *(const uint4*)(hbf + (size_t)gr * 128 + chunk * 8);
        *(uint4*)&As[r * 128 + ((chunk * 8) ^ ((r & 7) << 3))] = val;
    }
    for (int it = 0; it < 8; it++) {
        int r = r0 + it * 16;
        uint4 val = *(const uint4*)(B1 + (size_t)r * 128 + chunk * 8);
        *(uint4*)&Bs[r * 128 + ((chunk * 8) ^ ((r & 7) << 3))] = val;
    }
    __syncthreads();

    int w = tid >> 6, l = tid & 63;
    int lr = l & 15, lq = l >> 4;
    bf16x8 a[4];
    int ar = w * 16 + lr;
    for (int kk = 0; kk < 4; kk++)
        a[kk] = *(const bf16x8*)&As[ar * 128 + ((kk * 32 + lq * 8) ^ ((ar & 7) << 3))];

    for (int ct = 0; ct < 8; ct++) {
        int br = ct * 16 + lr;
        f32x4 acc = {0.f, 0.f, 0.f, 0.f};
        for (int kk = 0; kk < 4; kk++) {
            bf16x8 b = *(const bf16x8*)&Bs[br * 128 + ((kk * 32 + lq * 8) ^ ((br & 7) << 3))];
            acc = __builtin_amdgcn_mfma_f32_16x16x32_bf16(a[kk], b, acc, 0, 0, 0);
        }
        int j = ct * 16 + lr;
        for (int ri = 0; ri < 4; ri++) {
            int row = rowBase + w * 16 + lq * 4 + ri;
            if (row < N) g[(size_t)row * 128 + j] = f2bf(acc[ri]);
        }
    }
}

// ---------------- fused edge kernel: one wave per dst, 4 edges/iter ----------
// 16-lane group per edge; lane covers 8 elems (uint4). Aggregates h[src] rows
// (Wv folded into output GEMM), so the loaded hv is reused for the accumulate.
__launch_bounds__(256)
__global__ void k_edge(const u16* __restrict__ g, const u16* __restrict__ hbf,
                       const int* __restrict__ offs, const int* __restrict__ esrc,
                       u16* __restrict__ agg, int N) {
    int wid = (blockIdx.x * blockDim.x + threadIdx.x) >> 6;
    int lane = threadIdx.x & 63;
    if (wid >= N) return;
    int sub = lane >> 4;    // edge slot 0..3
    int sl  = lane & 15;    // lane within group; covers u32s [sl*4, sl*4+4)
    const uint4* g16 = (const uint4*)g;
    const uint4* h16 = (const uint4*)hbf;

    uint4 gv = g16[(size_t)wid * 16 + sl];
    float gf0 = bf2f(gv.x & 0xffff), gf1 = bf2f(gv.x >> 16);
    float gf2 = bf2f(gv.y & 0xffff), gf3 = bf2f(gv.y >> 16);
    float gf4 = bf2f(gv.z & 0xffff), gf5 = bf2f(gv.z >> 16);
    float gf6 = bf2f(gv.w & 0xffff), gf7 = bf2f(gv.w >> 16);

    int e0 = offs[wid], e1 = offs[wid + 1];
    float acc[8] = {0.f, 0.f, 0.f, 0.f, 0.f, 0.f, 0.f, 0.f};
    float denom = 0.f;
    const float sc = 0.08838834764831845f;  // 1/sqrt(128)

    for (int base = e0; base < e1; base += 4) {
        int i = base + sub;
        bool act = (i < e1);
        int src = act ? esrc[i] : 0;
        uint4 hv = h16[(size_t)src * 16 + sl];
        float h0 = bf2f(hv.x & 0xffff), h1 = bf2f(hv.x >> 16);
        float h2 = bf2f(hv.y & 0xffff), h3 = bf2f(hv.y >> 16);
        float h4 = bf2f(hv.z & 0xffff), h5 = bf2f(hv.z >> 16);
        float h6 = bf2f(hv.w & 0xffff), h7 = bf2f(hv.w >> 16);
        float p = gf0 * h0 + gf1 * h1 + gf2 * h2 + gf3 * h3
                + gf4 * h4 + gf5 * h5 + gf6 * h6 + gf7 * h7;
        p += __shfl_xor(p, 1, 64);
        p += __shfl_xor(p, 2, 64);
        p += __shfl_xor(p, 4, 64);
        p += __shfl_xor(p, 8, 64);
        float ew = act ? __expf(p * sc) : 0.f;
        denom += ew;
        acc[0] += ew * h0; acc[1] += ew * h1;
        acc[2] += ew * h2; acc[3] += ew * h3;
        acc[4] += ew * h4; acc[5] += ew * h5;
        acc[6] += ew * h6; acc[7] += ew * h7;
    }

    // cross-group reduce (groups hold same element positions)
    for (int m = 16; m < 64; m <<= 1) {
        denom += __shfl_xor(denom, m, 64);
        for (int k = 0; k < 8; k++) acc[k] += __shfl_xor(acc[k], m, 64);
    }

    if (sub == 0) {
        float inv = (denom > 0.f) ? 1.f / denom : 0.f;
        uint4 o;
        o.x = ((u32)f2bf(acc[1] * inv) << 16) | f2bf(acc[0] * inv);
        o.y = ((u32)f2bf(acc[3] * inv) << 16) | f2bf(acc[2] * inv);
        o.z = ((u32)f2bf(acc[5] * inv) << 16) | f2bf(acc[4] * inv);
        o.w = ((u32)f2bf(acc[7] * inv) << 16) | f2bf(acc[6] * inv);
        ((uint4*)agg)[(size_t)wid * 16 + sl] = o;
    }
}

// ---------------- GEMM2: out = relu(agg @ Wpv^T + bp + h)  (f32 out) ---------
// residual read from hbf (bf16): adds <=~0.02 abs error, saves 25.6 MB f32 read
__launch_bounds__(256)
__global__ void k_gemm2(const u16* __restrict__ aggbf, const u16* __restrict__ Wpv,
                        const float* __restrict__ bp, const u16* __restrict__ hbf,
                        float* __restrict__ out, int N) {
    __shared__ u16 As[64 * 128];    // 16 KB
    __shared__ u16 Bs[128 * 128];   // 32 KB
    int tid = threadIdx.x;
    int rowBase = blockIdx.x * 64;
    int chunk = tid & 15, r0 = tid >> 4;

    for (int it = 0; it < 4; it++) {
        int r = r0 + it * 16;
        int gr = rowBase + r;
        uint4 val = make_uint4(0, 0, 0, 0);
        if (gr < N) val = *(const uint4*)(aggbf + (size_t)gr * 128 + chunk * 8);
        *(uint4*)&As[r * 128 + ((chunk * 8) ^ ((r & 7) << 3))] = val;
    }
    for (int it = 0; it < 8; it++) {
        int r = r0 + it * 16;
        uint4 val = *(const uint4*)(Wpv + (size_t)r * 128 + chunk * 8);
        *(uint4*)&Bs[r * 128 + ((chunk * 8) ^ ((r & 7) << 3))] = val;
    }
    __syncthreads();

    int w = tid >> 6, l = tid & 63;
    int lr = l & 15, lq = l >> 4;
    bf16x8 a[4];
    int ar = w * 16 + lr;
    for (int kk = 0; kk < 4; kk++)
        a[kk] = *(const bf16x8*)&As[ar * 128 + ((kk * 32 + lq * 8) ^ ((ar & 7) << 3))];

    for (int ct = 0; ct < 8; ct++) {
        int br = ct * 16 + lr;
        f32x4 acc = {0.f, 0.f, 0.f, 0.f};
        for (int kk = 0; kk < 4; kk++) {
            bf16x8 b = *(const bf16x8*)&Bs[br * 128 + ((kk * 32 + lq * 8) ^ ((br & 7) << 3))];
            acc = __builtin_amdgcn_mfma_f32_16x16x32_bf16(a[kk], b, acc, 0, 0, 0);
        }
        int j = ct * 16 + lr;
        float bj = bp[j];
        for (int ri = 0; ri < 4; ri++) {
            int row = rowBase + w * 16 + lq * 4 + ri;
            if (row < N) {
                float res = bf2f(hbf[(size_t)row * 128 + j]);
                float val = acc[ri] + bj + res;
                out[(size_t)row * 128 + j] = fmaxf(val, 0.f);
            }
        }
    }
}

extern "C" void kernel_launch(void* const* d_in, const int* in_sizes, int n_in,
                              void* d_out, int out_size, void* d_ws, size_t ws_size,
                              hipStream_t stream) {
    const float* h  = (const float*)d_in[0];
    const int* edges = (const int*)d_in[1];
    const float* Wq = (const float*)d_in[2];
    const float* Wk = (const float*)d_in[3];
    const float* Wv = (const float*)d_in[4];
    const float* Wp = (const float*)d_in[5];
    const float* bp = (const float*)d_in[6];
    float* out = (float*)d_out;

    int N = in_sizes[0] / 128;
    int E = in_sizes[1] / 2;

    char* ws = (char*)d_ws;
    size_t off = 0;
    auto alloc = [&](size_t bytes) -> char* {
        char* p = ws + off;
        off = (off + bytes + 255) & ~(size_t)255;
        return p;
    };
    u16* hbf  = (u16*)alloc((size_t)N * 128 * 2);
    u16* B1   = (u16*)alloc(128 * 128 * 2);
    u16* Wpv  = (u16*)alloc(128 * 128 * 2);
    u16* g    = (u16*)alloc((size_t)N * 128 * 2);
    u16* agg  = (u16*)alloc((size_t)N * 128 * 2);
    int* deg   = (int*)alloc((size_t)N * 4);
    int* offs  = (int*)alloc((size_t)(N + 1) * 4);
    int* erank = (int*)alloc((size_t)E * 4);
    int* esrc  = (int*)alloc((size_t)E * 4);
    int* bsum  = (int*)alloc(256 * 4);
    (void)ws_size; (void)n_in; (void)out_size;

    hipMemsetAsync(deg, 0, (size_t)N * 4, stream);

    int NB = (N + 1023) / 1024;   // 98 for N=100k (<=256 supported)
    int total = N * 128;
    k_conv_h<<<(total / 4 + 255) / 256, 256, 0, stream>>>(h, hbf, total);
    k_prep<<<256, 128, 0, stream>>>(Wq, Wk, Wv, Wp, B1, Wpv);
    k_hist<<<(E + 255) / 256, 256, 0, stream>>>(edges, deg, erank, E);
    k_scan_part<<<NB, 256, 0, stream>>>(deg, bsum, N);
    k_scan_top<<<1, 256, 0, stream>>>(bsum, offs, NB, N);
    k_scan_down<<<NB, 256, 0, stream>>>(deg, bsum, offs, N);
    k_scatter<<<(E + 255) / 256, 256, 0, stream>>>(edges, offs, erank, esrc, E);
    k_gemm1<<<(N + 63) / 64, 256, 0, stream>>>(hbf, B1, g, N);
    k_edge<<<(N + 3) / 4, 256, 0, stream>>>(g, hbf, offs, esrc, agg, N);
    k_gemm2<<<(N + 63) / 64, 256, 0, stream>>>(agg, Wpv, bp, hbf, out, N);
}

// Round 11
// 246.905 us; speedup vs baseline: 2.2312x; 1.0279x over previous
//
#include <hip/hip_runtime.h>
#include <hip/hip_bf16.h>

typedef unsigned short u16;
typedef unsigned int u32;
typedef short bf16x8 __attribute__((ext_vector_type(8)));
typedef float f32x4 __attribute__((ext_vector_type(4)));
typedef float f32x2 __attribute__((ext_vector_type(2)));

__device__ __forceinline__ float bf2f(u32 bits16) {
    return __uint_as_float(bits16 << 16);
}
__device__ __forceinline__ u16 f2bf(float f) {
    u32 u = __float_as_uint(f);
    u32 r = (u + 0x7fffu + ((u >> 16) & 1u)) >> 16;   // RNE
    return (u16)r;
}
// unpack bf16 pair (u32) -> packed float2 {lo, hi}
__device__ __forceinline__ f32x2 unpk(u32 v) {
    f32x2 r;
    r.x = __uint_as_float(v << 16);
    r.y = __uint_as_float(v & 0xffff0000u);
    return r;
}

// ---------------- build B1 = M^T = (Wq^T Wk)^T rows (128x128 bf16),
//                  Wpv = Wp @ Wv (128x128 bf16) ----------------
__global__ void k_prep(const float* __restrict__ Wq, const float* __restrict__ Wk,
                       const float* __restrict__ Wv, const float* __restrict__ Wp,
                       u16* __restrict__ B1, u16* __restrict__ Wpv) {
    int j = blockIdx.x;
    int k = threadIdx.x;  // 128 threads
    if (j < 128) {
        float s = 0.f;
        for (int t = 0; t < 128; t++) s += Wq[t * 128 + k] * Wk[t * 128 + j];
        B1[j * 128 + k] = f2bf(s);
    } else {
        int m = j - 128;
        float s = 0.f;
        for (int t = 0; t < 128; t++) s += Wp[m * 128 + t] * Wv[t * 128 + k];
        Wpv[m * 128 + k] = f2bf(s);
    }
}

// ---------------- degree histogram + per-edge rank ----------------
__global__ void k_hist(const int* __restrict__ edges, int* __restrict__ deg,
                       int* __restrict__ erank, int E) {
    int e = blockIdx.x * blockDim.x + threadIdx.x;
    if (e < E) {
        int dst = edges[E + e];
        erank[e] = atomicAdd(&deg[dst], 1);
    }
}

// ---------------- hierarchical exclusive scan ----------------
__global__ void k_scan_part(const int* __restrict__ deg, int* __restrict__ bsum, int N) {
    __shared__ int red[256];
    int b = blockIdx.x, t = threadIdx.x;
    int i0 = b * 1024 + t * 4;
    int s = 0;
    if (i0 + 3 < N) {
        int4 v = *(const int4*)(deg + i0);
        s = v.x + v.y + v.z + v.w;
    } else {
        for (int k = 0; k < 4; k++) if (i0 + k < N) s += deg[i0 + k];
    }
    red[t] = s;
    __syncthreads();
    for (int off = 128; off > 0; off >>= 1) {
        if (t < off) red[t] += red[t + off];
        __syncthreads();
    }
    if (t == 0) bsum[b] = red[0];
}

__global__ void k_scan_top(int* __restrict__ bsum, int* __restrict__ offs, int NB, int N) {
    __shared__ int tmp[256];
    int t = threadIdx.x;
    int v = (t < NB) ? bsum[t] : 0;
    tmp[t] = v;
    __syncthreads();
    for (int off = 1; off < 256; off <<= 1) {
        int cur = tmp[t];
        int a = (t >= off) ? tmp[t - off] : 0;
        __syncthreads();
        tmp[t] = cur + a;
        __syncthreads();
    }
    if (t < NB) bsum[t] = tmp[t] - v;   // exclusive
    if (t == 255) offs[N] = tmp[255];   // total = E
}

__global__ void k_scan_down(const int* __restrict__ deg, const int* __restrict__ bsum,
                            int* __restrict__ offs, int N) {
    __shared__ int tmp[256];
    int b = blockIdx.x, t = threadIdx.x;
    int i0 = b * 1024 + t * 4;
    int d0 = 0, d1 = 0, d2 = 0, d3 = 0;
    if (i0 + 3 < N) {
        int4 v = *(const int4*)(deg + i0);
        d0 = v.x; d1 = v.y; d2 = v.z; d3 = v.w;
    } else {
        if (i0 < N)     d0 = deg[i0];
        if (i0 + 1 < N) d1 = deg[i0 + 1];
        if (i0 + 2 < N) d2 = deg[i0 + 2];
        if (i0 + 3 < N) d3 = deg[i0 + 3];
    }
    int s = d0 + d1 + d2 + d3;
    tmp[t] = s;
    __syncthreads();
    for (int off = 1; off < 256; off <<= 1) {
        int cur = tmp[t];
        int a = (t >= off) ? tmp[t - off] : 0;
        __syncthreads();
        tmp[t] = cur + a;
        __syncthreads();
    }
    int run = bsum[b] + tmp[t] - s;   // exclusive prefix for this thread's 4
    if (i0 < N)     offs[i0]     = run; run += d0;
    if (i0 + 1 < N) offs[i0 + 1] = run; run += d1;
    if (i0 + 2 < N) offs[i0 + 2] = run; run += d2;
    if (i0 + 3 < N) offs[i0 + 3] = run;
}

// ---------------- scatter edge srcs into CSR (no atomics; uses erank) --------
__global__ void k_scatter(const int* __restrict__ edges, const int* __restrict__ offs,
                          const int* __restrict__ erank, int* __restrict__ esrc, int E) {
    int e = blockIdx.x * blockDim.x + threadIdx.x;
    if (e < E) {
        int dst = edges[E + e];
        esrc[offs[dst] + erank[e]] = edges[e];
    }
}

// ---------------- GEMM1 fused with h->bf16 conversion ----------------
// reads f32 h; writes hbf (bf16 copy, used by k_edge / gemm2) and g = hbf @ B1^T
__launch_bounds__(256)
__global__ void k_gemm1f(const float* __restrict__ h, const u16* __restrict__ B1,
                         u16* __restrict__ hbf, u16* __restrict__ g, int N) {
    __shared__ u16 As[64 * 128];    // 16 KB, swizzled
    __shared__ u16 Bs[128 * 128];   // 32 KB, swizzled
    int tid = threadIdx.x;
    int rowBase = blockIdx.x * 64;
    int chunk = tid & 15, r0 = tid >> 4;

    for (int it = 0; it < 4; it++) {
        int r = r0 + it * 16;
        int gr = rowBase + r;
        uint4 val = make_uint4(0, 0, 0, 0);
        if (gr < N) {
            const float* src = h + (size_t)gr * 128 + chunk * 8;
            float4 f0 = *(const float4*)(src);
            float4 f1 = *(const float4*)(src + 4);
            val.x = ((u32)f2bf(f0.y) << 16) | f2bf(f0.x);
            val.y = ((u32)f2bf(f0.w) << 16) | f2bf(f0.z);
            val.z = ((u32)f2bf(f1.y) << 16) | f2bf(f1.x);
            val.w = ((u32)f2bf(f1.w) << 16) | f2bf(f1.z);
            *(uint4*)(hbf + (size_t)gr * 128 + chunk * 8) = val;
        }
        *(uint4*)&As[r * 128 + ((chunk * 8) ^ ((r & 7) << 3))] = val;
    }
    for (int it = 0; it < 8; it++) {
        int r = r0 + it * 16;
        uint4 val = *(const uint4*)(B1 + (size_t)r * 128 + chunk * 8);
        *(uint4*)&Bs[r * 128 + ((chunk * 8) ^ ((r & 7) << 3))] = val;
    }
    __syncthreads();

    int w = tid >> 6, l = tid & 63;
    int lr = l & 15, lq = l >> 4;
    bf16x8 a[4];
    int ar = w * 16 + lr;
    for (int kk = 0; kk < 4; kk++)
        a[kk] = *(const bf16x8*)&As[ar * 128 + ((kk * 32 + lq * 8) ^ ((ar & 7) << 3))];

    for (int ct = 0; ct < 8; ct++) {
        int br = ct * 16 + lr;
        f32x4 acc = {0.f, 0.f, 0.f, 0.f};
        for (int kk = 0; kk < 4; kk++) {
            bf16x8 b = *(const bf16x8*)&Bs[br * 128 + ((kk * 32 + lq * 8) ^ ((br & 7) << 3))];
            acc = __builtin_amdgcn_mfma_f32_16x16x32_bf16(a[kk], b, acc, 0, 0, 0);
        }
        int j = ct * 16 + lr;
        for (int ri = 0; ri < 4; ri++) {
            int row = rowBase + w * 16 + lq * 4 + ri;
            if (row < N) g[(size_t)row * 128 + j] = f2bf(acc[ri]);
        }
    }
}

// ---------------- fused edge kernel: one wave per dst, 4 edges/iter ----------
// 16-lane group per edge; lane covers 8 elems (uint4). Packed f32x2 math
// (v_pk_fma_f32) for dot + accumulate; h unpacked once, reused for both.
__launch_bounds__(256)
__global__ void k_edge(const u16* __restrict__ g, const u16* __restrict__ hbf,
                       const int* __restrict__ offs, const int* __restrict__ esrc,
                       u16* __restrict__ agg, int N) {
    int wid = (blockIdx.x * blockDim.x + threadIdx.x) >> 6;
    int lane = threadIdx.x & 63;
    if (wid >= N) return;
    int sub = lane >> 4;    // edge slot 0..3
    int sl  = lane & 15;    // lane within group; covers u32s [sl*4, sl*4+4)
    const uint4* g16 = (const uint4*)g;
    const uint4* h16 = (const uint4*)hbf;

    uint4 gv = g16[(size_t)wid * 16 + sl];
    f32x2 gf0 = unpk(gv.x), gf1 = unpk(gv.y), gf2 = unpk(gv.z), gf3 = unpk(gv.w);

    int e0 = offs[wid], e1 = offs[wid + 1];
    f32x2 a0 = {0.f, 0.f}, a1 = {0.f, 0.f}, a2 = {0.f, 0.f}, a3 = {0.f, 0.f};
    float denom = 0.f;
    const float sc = 0.08838834764831845f;  // 1/sqrt(128)

    for (int base = e0; base < e1; base += 4) {
        int i = base + sub;
        bool act = (i < e1);
        int src = act ? esrc[i] : 0;
        uint4 hv = h16[(size_t)src * 16 + sl];
        f32x2 h0 = unpk(hv.x), h1 = unpk(hv.y), h2 = unpk(hv.z), h3 = unpk(hv.w);
        f32x2 ps = gf0 * h0;
        ps += gf1 * h1;
        ps += gf2 * h2;
        ps += gf3 * h3;
        float p = ps.x + ps.y;
        p += __shfl_xor(p, 1, 64);
        p += __shfl_xor(p, 2, 64);
        p += __shfl_xor(p, 4, 64);
        p += __shfl_xor(p, 8, 64);
        float ew = act ? __expf(p * sc) : 0.f;
        denom += ew;
        f32x2 ew2 = {ew, ew};
        a0 += ew2 * h0;
        a1 += ew2 * h1;
        a2 += ew2 * h2;
        a3 += ew2 * h3;
    }

    // cross-group reduce (groups hold same element positions)
    for (int m = 16; m < 64; m <<= 1) {
        denom += __shfl_xor(denom, m, 64);
        a0.x += __shfl_xor(a0.x, m, 64); a0.y += __shfl_xor(a0.y, m, 64);
        a1.x += __shfl_xor(a1.x, m, 64); a1.y += __shfl_xor(a1.y, m, 64);
        a2.x += __shfl_xor(a2.x, m, 64); a2.y += __shfl_xor(a2.y, m, 64);
        a3.x += __shfl_xor(a3.x, m, 64); a3.y += __shfl_xor(a3.y, m, 64);
    }

    if (sub == 0) {
        float inv = (denom > 0.f) ? 1.f / denom : 0.f;
        uint4 o;
        o.x = ((u32)f2bf(a0.y * inv) << 16) | f2bf(a0.x * inv);
        o.y = ((u32)f2bf(a1.y * inv) << 16) | f2bf(a1.x * inv);
        o.z = ((u32)f2bf(a2.y * inv) << 16) | f2bf(a2.x * inv);
        o.w = ((u32)f2bf(a3.y * inv) << 16) | f2bf(a3.x * inv);
        ((uint4*)agg)[(size_t)wid * 16 + sl] = o;
    }
}

// ---------------- GEMM2: out = relu(agg @ Wpv^T + bp + h)  (f32 out) ---------
__launch_bounds__(256)
__global__ void k_gemm2(const u16* __restrict__ aggbf, const u16* __restrict__ Wpv,
                        const float* __restrict__ bp, const u16* __restrict__ hbf,
                        float* __restrict__ out, int N) {
    __shared__ u16 As[64 * 128];    // 16 KB
    __shared__ u16 Bs[128 * 128];   // 32 KB
    int tid = threadIdx.x;
    int rowBase = blockIdx.x * 64;
    int chunk = tid & 15, r0 = tid >> 4;

    for (int it = 0; it < 4; it++) {
        int r = r0 + it * 16;
        int gr = rowBase + r;
        uint4 val = make_uint4(0, 0, 0, 0);
        if (gr < N) val = *(const uint4*)(aggbf + (size_t)gr * 128 + chunk * 8);
        *(uint4*)&As[r * 128 + ((chunk * 8) ^ ((r & 7) << 3))] = val;
    }
    for (int it = 0; it < 8; it++) {
        int r = r0 + it * 16;
        uint4 val = *(const uint4*)(Wpv + (size_t)r * 128 + chunk * 8);
        *(uint4*)&Bs[r * 128 + ((chunk * 8) ^ ((r & 7) << 3))] = val;
    }
    __syncthreads();

    int w = tid >> 6, l = tid & 63;
    int lr = l & 15, lq = l >> 4;
    bf16x8 a[4];
    int ar = w * 16 + lr;
    for (int kk = 0; kk < 4; kk++)
        a[kk] = *(const bf16x8*)&As[ar * 128 + ((kk * 32 + lq * 8) ^ ((ar & 7) << 3))];

    for (int ct = 0; ct < 8; ct++) {
        int br = ct * 16 + lr;
        f32x4 acc = {0.f, 0.f, 0.f, 0.f};
        for (int kk = 0; kk < 4; kk++) {
            bf16x8 b = *(const bf16x8*)&Bs[br * 128 + ((kk * 32 + lq * 8) ^ ((br & 7) << 3))];
            acc = __builtin_amdgcn_mfma_f32_16x16x32_bf16(a[kk], b, acc, 0, 0, 0);
        }
        int j = ct * 16 + lr;
        float bj = bp[j];
        for (int ri = 0; ri < 4; ri++) {
            int row = rowBase + w * 16 + lq * 4 + ri;
            if (row < N) {
                float res = bf2f(hbf[(size_t)row * 128 + j]);
                float val = acc[ri] + bj + res;
                out[(size_t)row * 128 + j] = fmaxf(val, 0.f);
            }
        }
    }
}

extern "C" void kernel_launch(void* const* d_in, const int* in_sizes, int n_in,
                              void* d_out, int out_size, void* d_ws, size_t ws_size,
                              hipStream_t stream) {
    const float* h  = (const float*)d_in[0];
    const int* edges = (const int*)d_in[1];
    const float* Wq = (const float*)d_in[2];
    const float* Wk = (const float*)d_in[3];
    const float* Wv = (const float*)d_in[4];
    const float* Wp = (const float*)d_in[5];
    const float* bp = (const float*)d_in[6];
    float* out = (float*)d_out;

    int N = in_sizes[0] / 128;
    int E = in_sizes[1] / 2;

    char* ws = (char*)d_ws;
    size_t off = 0;
    auto alloc = [&](size_t bytes) -> char* {
        char* p = ws + off;
        off = (off + bytes + 255) & ~(size_t)255;
        return p;
    };
    u16* hbf  = (u16*)alloc((size_t)N * 128 * 2);
    u16* B1   = (u16*)alloc(128 * 128 * 2);
    u16* Wpv  = (u16*)alloc(128 * 128 * 2);
    u16* g    = (u16*)alloc((size_t)N * 128 * 2);
    u16* agg  = (u16*)alloc((size_t)N * 128 * 2);
    int* deg   = (int*)alloc((size_t)N * 4);
    int* offs  = (int*)alloc((size_t)(N + 1) * 4);
    int* erank = (int*)alloc((size_t)E * 4);
    int* esrc  = (int*)alloc((size_t)E * 4);
    int* bsum  = (int*)alloc(256 * 4);
    (void)ws_size; (void)n_in; (void)out_size;

    hipMemsetAsync(deg, 0, (size_t)N * 4, stream);

    int NB = (N + 1023) / 1024;   // 98 for N=100k (<=256 supported)
    k_prep<<<256, 128, 0, stream>>>(Wq, Wk, Wv, Wp, B1, Wpv);
    k_hist<<<(E + 255) / 256, 256, 0, stream>>>(edges, deg, erank, E);
    k_scan_part<<<NB, 256, 0, stream>>>(deg, bsum, N);
    k_scan_top<<<1, 256, 0, stream>>>(bsum, offs, NB, N);
    k_scan_down<<<NB, 256, 0, stream>>>(deg, bsum, offs, N);
    k_scatter<<<(E + 255) / 256, 256, 0, stream>>>(edges, offs, erank, esrc, E);
    k_gemm1f<<<(N + 63) / 64, 256, 0, stream>>>(h, B1, hbf, g, N);
    k_edge<<<(N + 3) / 4, 256, 0, stream>>>(g, hbf, offs, esrc, agg, N);
    k_gemm2<<<(N + 63) / 64, 256, 0, stream>>>(agg, Wpv, bp, hbf, out, N);
}